// Round 9
// baseline (1362.907 us; speedup 1.0000x reference)
//
#include <hip/hip_runtime.h>

typedef __attribute__((ext_vector_type(8))) short short8;
typedef __attribute__((ext_vector_type(4))) float f32x4;
typedef unsigned short u16;
typedef unsigned int u32;
typedef unsigned long long u64;

#define T_LEN 256
#define XSTEP_U16 32768      // x/y per-t: [sbb:4][kt:16][512] u16 = 64KB
#define GSTEP_U16 8192       // per-group per-slot: [kt:16][512] u16 = 16KB

// workspace layout (bytes)
#define OFF_X0 0u
#define SZ_X0 (256u * 65536u)   // 16MB
#define OFF_Y0 (OFF_X0 + SZ_X0)
#define SZ_Y0 SZ_X0             // 16MB
#define OFF_HD (OFF_Y0 + SZ_Y0)
#define SZ_HD (8u * 2u * 16384u)  // 8 groups x 2 slots x 16KB = 256KB
#define OFF_POOL (OFF_HD + SZ_HD)
#define SZ_POOL (512u * 64u * 4u)
#define OFF_HFLG (OFF_POOL + SZ_POOL)
#define SZ_HFLG (8u * 16u * 4u)   // [group][16 blocks]
#define OFF_YFLG (OFF_HFLG + SZ_HFLG)
#define SZ_YFLG (4u * 16u * 4u)   // [sbb][16 blocks]
#define OFF_XMAP (OFF_YFLG + SZ_YFLG)
#define SZ_XMAP (8u * 16u * 4u)   // [group][16] published XCC ids

__device__ __forceinline__ u16 f2bf(float x) {
  unsigned u = __builtin_bit_cast(unsigned, x);
  return (u16)((u + 0x7fffu + ((u >> 16) & 1u)) >> 16);
}
__device__ __forceinline__ float sigf(float x) { return 1.f / (1.f + __expf(-x)); }
__device__ __forceinline__ float tanhfast(float x) {
  float e = __expf(2.f * x);
  return 1.f - 2.f / (e + 1.f);
}

// sc1 (LLC-coherent) primitives — the proven slow/global path
__device__ __forceinline__ short8 ld16_llc(const u16* p) {
  const u64* q = (const u64*)p;
  u64 lo = __hip_atomic_load(q + 0, __ATOMIC_RELAXED, __HIP_MEMORY_SCOPE_AGENT);
  u64 hi = __hip_atomic_load(q + 1, __ATOMIC_RELAXED, __HIP_MEMORY_SCOPE_AGENT);
  union { u64 v[2]; short8 s; } u;
  u.v[0] = lo; u.v[1] = hi;
  return u.s;
}
__device__ __forceinline__ void st2_llc(u16* p, u16 v) {
  __hip_atomic_store(p, v, __ATOMIC_RELAXED, __HIP_MEMORY_SCOPE_AGENT);
}
__device__ __forceinline__ void poll_sc1(const u32* base, int lane, u32 tgt, bool slp) {
  const u32* pf = base + (lane & 15);
  for (;;) {
    u32 v = __hip_atomic_load(pf, __ATOMIC_RELAXED, __HIP_MEMORY_SCOPE_AGENT);
    if (__all((int)(v >= tgt))) break;
    if (slp) __builtin_amdgcn_s_sleep(1);
  }
  asm volatile("" ::: "memory");
}
// intra-XCD fast poll: invalidate own L1, plain load from shared L2
__device__ __forceinline__ void poll_fast(const u32* base, int lane, u32 tgt) {
  const volatile u32* pf = base + (lane & 15);
  for (;;) {
    asm volatile("buffer_inv" ::: "memory");
    u32 v = *pf;
    if (__all((int)(v >= tgt))) break;
  }
  asm volatile("" ::: "memory");
}

__device__ __forceinline__ short8 cvt8(const float* src) {
  float4 lo = *(const float4*)src;
  float4 hi = *(const float4*)(src + 4);
  short8 fr;
  fr[0] = (short)f2bf(lo.x); fr[1] = (short)f2bf(lo.y);
  fr[2] = (short)f2bf(lo.z); fr[3] = (short)f2bf(lo.w);
  fr[4] = (short)f2bf(hi.x); fr[5] = (short)f2bf(hi.y);
  fr[6] = (short)f2bf(hi.z); fr[7] = (short)f2bf(hi.w);
  return fr;
}

// ---- embedding gather into MFMA-B fragment layout (bf16) ----
// chunk c = t*64 + sbb*16 + kt; lane -> n = lane&15 (sample in sbb), k = kt*32+(lane>>4)*8+j
__global__ void gather_x0(const int* __restrict__ in_t, const float* __restrict__ emb,
                          u16* __restrict__ x0) {
  int gid = blockIdx.x * 256 + threadIdx.x;
  int c = gid >> 6, lane = gid & 63;
  int t = c >> 6, rem = c & 63;
  int sbb = rem >> 4, kt = rem & 15;
  int b = sbb * 16 + (lane & 15);
  int k0 = kt * 32 + ((lane >> 4) * 8);
  int row = in_t[b * T_LEN + t];
  *(short8*)(x0 + (size_t)c * 512 + lane * 8) = cvt8(emb + (size_t)row * 512 + k0);
}

// ---- main loop body, specialized on exchange path ----
// group g = (layer, sbb): 16 blocks, 16 samples, all 512 h. Block i owns h [32i,32i+32)
// (128 gate-rows, m = 4*h_local + gate). Waves: w<2 x-side (Wx K 0..511),
// w>=2 h-side (Wh). Each wave: 8 m-tiles x 8 k-steps = 64 MFMA/step.
template <bool FAST>
__device__ __forceinline__ void run_loop(
    int layer, int sbb, int i, int w, int lane, int tid,
    const float* __restrict__ wx, const float* __restrict__ bx,
    const float* __restrict__ wh, const float* __restrict__ bh,
    const u16* __restrict__ x0, u16* __restrict__ y0,
    u16* __restrict__ hd, float* __restrict__ pool,
    u32* __restrict__ hflg, u32* __restrict__ yflg,
    float (*part)[128][17]) {
  const int q = lane >> 4, col = lane & 15;
  const int side = w >> 1;

  // weight fragments: 8 m-tiles x 8 ks = 256 regs (straight-line, const-indexed)
  short8 afrag[8][8];
  {
    const int gt = col & 3, hl4 = col >> 2;
    const int kb = (w & 1) * 256 + q * 8;
#pragma unroll
    for (int mt = 0; mt < 8; ++mt) {
      const int h_g = i * 32 + mt * 4 + hl4;
      const float* wrow = (side ? wh : wx) +
                          ((size_t)(layer * 4 + gt) * 512 + h_g) * 512;
#pragma unroll
      for (int ks = 0; ks < 8; ++ks)
        afrag[mt][ks] = cvt8(wrow + kb + ks * 32);
    }
  }
  // epilogue ownership: (h = 32i + hl + 16P, sample n), P in {0,1}
  const int hl = tid >> 4, n = tid & 15;
  float biasv[2][4];
  size_t offP[2];
#pragma unroll
  for (int P = 0; P < 2; ++P) {
    const int h_g = i * 32 + hl + 16 * P;
#pragma unroll
    for (int r = 0; r < 4; ++r)
      biasv[P][r] = bx[(layer * 4 + r) * 512 + h_g] + bh[(layer * 4 + r) * 512 + h_g];
    offP[P] = (size_t)i * 512 + (size_t)(16 * ((h_g >> 3) & 3) + n) * 8 + (h_g & 7);
  }

  const u16* xl = layer ? y0 : x0;
  u16* hdl = hd + (size_t)(layer * 4 + sbb) * 2 * GSTEP_U16;
  u32* hf_own = hflg + (layer * 4 + sbb) * 16 + i;
  const u32* hf_grp = hflg + (layer * 4 + sbb) * 16;
  u32* yf_own = yflg + sbb * 16 + i;
  const u32* yf_grp = yflg + sbb * 16;

  float cst0 = 0.f, cst1 = 0.f, op0 = 0.f, op1 = 0.f;

  for (int t = 0; t < T_LEN; ++t) {
    f32x4 acc[8] = {};
    if (side == 0) {
      if (layer == 1) poll_sc1(yf_grp, lane, (u32)(t + 1), true);
      const u16* xs = xl + (size_t)t * XSTEP_U16 + (size_t)sbb * GSTEP_U16;
#pragma unroll
      for (int ks = 0; ks < 8; ++ks) {
        const int kt = w * 8 + ks;
        const u16* p = xs + kt * 512 + lane * 8;
        short8 f = (layer == 0) ? *(const short8*)p : ld16_llc(p);
#pragma unroll
        for (int mt = 0; mt < 8; ++mt)
          acc[mt] = __builtin_amdgcn_mfma_f32_16x16x32_bf16(afrag[mt][ks], f,
                                                            acc[mt], 0, 0, 0);
      }
    } else {
      if (FAST) poll_fast(hf_grp, lane, (u32)t);
      else poll_sc1(hf_grp, lane, (u32)t, false);
      const u16* hs = hdl + (size_t)(t & 1) * GSTEP_U16;
#pragma unroll
      for (int ks = 0; ks < 8; ++ks) {
        const int kt = (w & 1) * 8 + ks;
        const u16* p = hs + kt * 512 + lane * 8;
        short8 f = FAST ? *(const short8*)p : ld16_llc(p);
#pragma unroll
        for (int mt = 0; mt < 8; ++mt)
          acc[mt] = __builtin_amdgcn_mfma_f32_16x16x32_bf16(afrag[mt][ks], f,
                                                            acc[mt], 0, 0, 0);
      }
    }
    // partials -> LDS (C/D: n = lane&15, m-row = 16mt + 4q + r)
#pragma unroll
    for (int mt = 0; mt < 8; ++mt)
#pragma unroll
      for (int r = 0; r < 4; ++r)
        part[w][16 * mt + 4 * q + r][col] = acc[mt][r];
    __syncthreads();   // b1: partials ready

    // epilogue: 4-wave reduce + gates; c stores first (h critical path)
    u16* hdst = hdl + (size_t)((t + 1) & 1) * GSTEP_U16;
    float ogv[2];
#pragma unroll
    for (int P = 0; P < 2; ++P) {
      const int rbase = 4 * (hl + 16 * P);
      float vg[4];
#pragma unroll
      for (int gt = 0; gt < 4; ++gt)
        vg[gt] = part[0][rbase + gt][n] + part[1][rbase + gt][n] +
                 part[2][rbase + gt][n] + part[3][rbase + gt][n] + biasv[P][gt];
      const float ig = sigf(vg[0]);
      const float fg = sigf(vg[1]);
      const float gg = tanhfast(vg[2]);
      const float og = sigf(vg[3]);
      const float cp = P ? cst1 : cst0;
      const float cn = fg * cp + ig * gg;   // c input = prev h_new (unpack bug)
      const float hn = og * tanhfast(cn);
      if (P) cst1 = hn; else cst0 = hn;
      ogv[P] = og;
      if (FAST) *(volatile u16*)(hdst + offP[P]) = f2bf(cn);  // plain -> L2
      else st2_llc(hdst + offP[P], f2bf(cn));
    }
    asm volatile("s_waitcnt vmcnt(0)" ::: "memory");  // c stores acked (L2 if FAST)
    __syncthreads();   // b2: all c stores acked; part[] fully read
    if (tid == 0) {
      if (FAST) *(volatile u32*)hf_own = (u32)(t + 1);
      else __hip_atomic_store(hf_own, (u32)(t + 1), __ATOMIC_RELAXED,
                              __HIP_MEMORY_SCOPE_AGENT);
    }
    if (layer == 0) {
      // y phase off the h critical path: sc1 (cross-XCD consumers, 1-step slack)
      u16* ydst = y0 + (size_t)t * XSTEP_U16 + (size_t)sbb * GSTEP_U16;
      st2_llc(ydst + offP[0], f2bf(ogv[0]));
      st2_llc(ydst + offP[1], f2bf(ogv[1]));
      asm volatile("s_waitcnt vmcnt(0)" ::: "memory");
      __syncthreads();   // b3: y stores acked
      if (tid == 1)
        __hip_atomic_store(yf_own, (u32)(t + 1), __ATOMIC_RELAXED,
                           __HIP_MEMORY_SCOPE_AGENT);
    } else {
      op0 += ogv[0]; op1 += ogv[1];
    }
  }

  if (layer == 1) {
    pool[(size_t)(i * 32 + hl) * 64 + sbb * 16 + n] = op0;
    pool[(size_t)(i * 32 + 16 + hl) * 64 + sbb * 16 + n] = op1;
  }
}

// ---- persistent kernel: publish XCC id, decide path per group, run ----
__global__ __launch_bounds__(256, 1) void lstm_persist(
    const float* __restrict__ wx, const float* __restrict__ bx,
    const float* __restrict__ wh, const float* __restrict__ bh,
    const u16* __restrict__ x0, u16* __restrict__ y0,
    u16* __restrict__ hd, float* __restrict__ pool,
    u32* __restrict__ hflg, u32* __restrict__ yflg, u32* __restrict__ xmap) {
  __shared__ float part[4][128][17];
  const int tid = threadIdx.x;
  const int w = tid >> 6, lane = tid & 63;
  const int bid = blockIdx.x;
  const int g = bid & 7;                 // expected XCD slot
  const int layer = g >> 2, sbb = g & 3;
  const int i = bid >> 3;                // 0..15

  // publish my XCC_ID (verified readable on MI355X)
  u32* map_g = xmap + g * 16;
  if (tid == 0) {
    u32 my;
    asm volatile("s_getreg_b32 %0, hwreg(HW_REG_XCC_ID)" : "=s"(my));
    __hip_atomic_store(map_g + i, my & 0xFu, __ATOMIC_RELAXED,
                       __HIP_MEMORY_SCOPE_AGENT);
  }
  // decide: fast iff all 16 group members on one XCD AND a foreign group differs
  const u32* map_f = xmap + (g ^ 4) * 16;
  bool fast;
  {
    u32 v, f0;
    for (;;) {
      v = __hip_atomic_load(map_g + (lane & 15), __ATOMIC_RELAXED,
                            __HIP_MEMORY_SCOPE_AGENT);
      f0 = __hip_atomic_load(map_f + (lane & 15), __ATOMIC_RELAXED,
                             __HIP_MEMORY_SCOPE_AGENT);
      if (__all((int)((v != 0xFFFFFFFFu) & (f0 != 0xFFFFFFFFu)))) break;
      __builtin_amdgcn_s_sleep(2);
    }
    u32 ref = __shfl(v, 0);
    bool same = __all((int)(v == ref));
    u32 fr = __shfl(f0, 0);
    fast = same && (fr != ref);
  }
  __syncthreads();

  if (fast)
    run_loop<true>(layer, sbb, i, w, lane, tid, wx, bx, wh, bh, x0, y0, hd,
                   pool, hflg, yflg, part);
  else
    run_loop<false>(layer, sbb, i, w, lane, tid, wx, bx, wh, bh, x0, y0, hd,
                    pool, hflg, yflg, part);
}

// ---- final pooled @ wo.T + bo -> sigmoid ----
__global__ void finalize_k(const float* __restrict__ pool, const float* __restrict__ wo,
                           const float* __restrict__ bo, float* __restrict__ out) {
  const int b = threadIdx.x;
  float s = 0.f;
  for (int h = 0; h < 512; ++h) s += pool[h * 64 + b] * wo[h];
  out[b] = sigf(s * (1.f / 256.f) + bo[0]);
}

extern "C" void kernel_launch(void* const* d_in, const int* in_sizes, int n_in,
                              void* d_out, int out_size, void* d_ws, size_t ws_size,
                              hipStream_t stream) {
  const int* in_t = (const int*)d_in[0];
  const float* emb = (const float*)d_in[1];
  const float* wx = (const float*)d_in[2];
  const float* bx = (const float*)d_in[3];
  const float* wh = (const float*)d_in[4];
  const float* bh = (const float*)d_in[5];
  const float* wo = (const float*)d_in[6];
  const float* bo = (const float*)d_in[7];
  float* out = (float*)d_out;
  char* ws = (char*)d_ws;
  u16* x0 = (u16*)(ws + OFF_X0);
  u16* y0 = (u16*)(ws + OFF_Y0);
  u16* hd = (u16*)(ws + OFF_HD);
  float* pool = (float*)(ws + OFF_POOL);
  u32* hflg = (u32*)(ws + OFF_HFLG);
  u32* yflg = (u32*)(ws + OFF_YFLG);
  u32* xmap = (u32*)(ws + OFF_XMAP);

  hipMemsetAsync(ws + OFF_HD, 0, SZ_HD, stream);                 // h(0) = 0
  hipMemsetAsync(ws + OFF_HFLG, 0, SZ_HFLG + SZ_YFLG, stream);   // step flags
  hipMemsetAsync(ws + OFF_XMAP, 0xFF, SZ_XMAP, stream);          // id markers
  gather_x0<<<4096, 256, 0, stream>>>(in_t, emb, x0);
  lstm_persist<<<128, 256, 0, stream>>>(wx, bx, wh, bh, x0, y0, hd, pool,
                                        hflg, yflg, xmap);
  finalize_k<<<1, 64, 0, stream>>>(pool, wo, bo, out);
}